// Round 8
// baseline (322.261 us; speedup 1.0000x reference)
//
#include <hip/hip_runtime.h>

#define Bb 64
#define Tt 256
#define Hh 512
#define Ww 1024
#define HW (Hh * Ww)          // 524288
#define EPSF 1e-5f

#define RB 4096               // one block per 8192-float chunk; 2 generations
#define CHUNK 8192            // svf floats owned per block (64 blocks/batch)

typedef float vf4 __attribute__((ext_vector_type(4)));

// ws layout (byte-identical footprint to prior rounds):
//   [0,256)         int    count[64]
//   [256,768)       double vdot[64]
//   [768,17152)     float  esum_p[4096]   (float partials are EXACT: each is
//   [17152,33536)   float  edot_p[4096]    itself a block-computed fp32 value)
// Everything is written before it is read -> no ws memset needed.

// ---------------------------------------------------------------------------
// Point computation (bit-identical to the reference at fp32)
// ---------------------------------------------------------------------------
__device__ __forceinline__ void comp_pt(const float* __restrict__ gt, int b,
                                        int idx, int ms, int segN,
                                        float& px, float& py) {
    if (idx < segN) {
        int seg = idx / ms;
        int k = idx - seg * ms;
        const float* g0 = gt + (size_t)(b * Tt + seg) * 9;
        float sx = g0[2] * 0.5f, sy = g0[5] * 0.5f;
        float ex = g0[11] * 0.5f, ey = g0[14] * 0.5f;
        float t = (ms > 1) ? (float)k / (float)(ms - 1) : 0.0f;
        px = __fadd_rn(sx, __fmul_rn(t, __fsub_rn(ex, sx)));
        py = __fadd_rn(sy, __fmul_rn(t, __fsub_rn(ey, sy)));
    } else {
        const float* g0 = gt + (size_t)(b * Tt + (Tt - 1)) * 9;
        px = g0[2] * 0.5f;
        py = g0[5] * 0.5f;
    }
}

__device__ __forceinline__ int pt_cell(float px, float py) {
    int xi = (int)fminf(fmaxf(px, 0.0f), (float)(Hh - 1));
    int yi = (int)fminf(fmaxf(py, 0.0f), (float)(Ww - 1));
    return xi * Ww + yi;
}

// ---- phase A: streaming exps/rew reduce over this block's chunk ----------
__device__ __forceinline__ void phaseA(const float* __restrict__ exps,
                                       const float* __restrict__ rew,
                                       size_t base, float& es, float& ed) {
    es = 0.0f; ed = 0.0f;
    const vf4* e4 = (const vf4*)(exps + base) + threadIdx.x;
    const vf4* r4 = (const vf4*)(rew  + base) + threadIdx.x;
    vf4 ev[8], rv[8];
    #pragma unroll
    for (int k = 0; k < 8; ++k) ev[k] = e4[k * 256];
    #pragma unroll
    for (int k = 0; k < 8; ++k) rv[k] = r4[k * 256];
    #pragma unroll
    for (int k = 0; k < 8; ++k) {
        vf4 e = ev[k], r = rv[k];
        es += (e.x + e.y) + (e.z + e.w);
        ed += (e.x * r.x + e.y * r.y) + (e.z * r.z + e.w * r.w);
    }
    for (int off = 32; off; off >>= 1) {
        es += __shfl_down(es, off);
        ed += __shfl_down(ed, off);
    }
}

// ---- phase B: plain zero-fill of this block's svf chunk ------------------
// svf = out+1 is only 4B-aligned: peel head/tail scalars around vf4 body.
__device__ __forceinline__ void phaseB(float* __restrict__ svf, size_t base) {
    float* p = svf + base;
    int head = (int)((16 - ((uintptr_t)p & 15)) & 15) >> 2;  // 0..3
    int nv   = (CHUNK - head) >> 2;
    int tail = CHUNK - head - (nv << 2);
    if ((int)threadIdx.x < head) p[threadIdx.x] = 0.0f;
    if ((int)threadIdx.x < tail) p[head + (nv << 2) + threadIdx.x] = 0.0f;
    vf4* v4 = (vf4*)(p + head);
    vf4 z = {0.0f, 0.0f, 0.0f, 0.0f};
    for (int k = (int)threadIdx.x; k < nv; k += 256) v4[k] = z;
}

// ---- phase C: per-batch dedup count (cells monotone -> adjacent-compare);
// designated block also writes pts and gathers vdot --------------------------
__device__ __forceinline__ void phaseC(const float* __restrict__ gt,
                                       const float* __restrict__ rew,
                                       float* __restrict__ pts,
                                       int b, int ms, int segN, int P,
                                       bool isScat, int& myCount, float& myV) {
    myCount = 0; myV = 0.0f;
    for (int idx = threadIdx.x; idx < P; idx += 256) {
        float px, py;
        comp_pt(gt, b, idx, ms, segN, px, py);
        int cell = pt_cell(px, py);
        bool claim;
        if (idx == 0) {
            claim = true;
        } else {
            float qx, qy;
            comp_pt(gt, b, idx - 1, ms, segN, qx, qy);
            claim = (pt_cell(qx, qy) != cell);
        }
        myCount += claim ? 1 : 0;
        if (isScat) {
            size_t pi = ((size_t)b * P + idx) * 2;
            pts[pi]     = px;
            pts[pi + 1] = py;
            if (claim) myV += rew[(size_t)b * HW + cell];
        }
    }
    for (int off = 32; off; off >>= 1) {
        myCount += __shfl_down(myCount, off);
        myV     += __shfl_down(myV, off);
    }
}

// ---------------------------------------------------------------------------
// Combined kernel: grid = 4096 blocks = TWO generations (round 5/7: 117 us).
// This round's single change: PHASE-ORDER STAGGER. All blocks previously ran
// A(read)->B(fill)->C(ALU) in chip-wide lockstep, so the HBM read path idled
// during the collective fill/ALU window. Alternating resident blocks (stagger
// bit (blk>>3)&1, chosen so consecutive blocks on one CU alternate given the
// blk%8 XCD striping) now run C->A->B: their reads overlap the other group's
// fill/ALU and vice versa. Order C,A,B (never fill-before-read: round 3
// measured +20us when loads queued behind stores in the vmcnt FIFO).
// Per-thread arithmetic is order-independent -> absmax stays 0.
// Block (b = blk>>6, c = blk&63) owns svf chunk [c*8192, (c+1)*8192) of
// batch b. Chunks disjoint -> no atomics, no cross-block races.
// ---------------------------------------------------------------------------
__global__ __launch_bounds__(256) void combined_kernel(
        const float* __restrict__ exps, const float* __restrict__ rew,
        const float* __restrict__ gt,
        float* __restrict__ pts, float* __restrict__ svf,
        float* __restrict__ esum_p, float* __restrict__ edot_p,
        int* __restrict__ count_out, double* __restrict__ vdot_out,
        int ms, int P) {
    int blk = blockIdx.x;
    int b = blk >> 6;
    int c = blk & 63;
    bool isScat = (c == b);          // designated scatter block for batch b
    int segN = (Tt - 1) * ms;
    size_t base = (size_t)b * HW + (size_t)c * CHUNK;

    float es, ed;
    int myCount;
    float myV;
    if (((blk >> 3) & 1) == 0) {
        phaseA(exps, rew, base, es, ed);
        phaseB(svf, base);
        phaseC(gt, rew, pts, b, ms, segN, P, isScat, myCount, myV);
    } else {
        phaseC(gt, rew, pts, b, ms, segN, P, isScat, myCount, myV);
        phaseA(exps, rew, base, es, ed);
        phaseB(svf, base);
    }

    __shared__ float s_es[4], s_ed[4];
    __shared__ float sv[4];
    __shared__ int   sc2[4];
    int lane = threadIdx.x & 63, wv = threadIdx.x >> 6;
    if (lane == 0) { s_es[wv] = es; s_ed[wv] = ed; sc2[wv] = myCount; sv[wv] = myV; }
    __syncthreads();   // publishes LDS partials AND drains phase-B stores
    if (threadIdx.x == 0) {
        esum_p[blk] = (s_es[0] + s_es[1]) + (s_es[2] + s_es[3]);
        edot_p[blk] = (s_ed[0] + s_ed[1]) + (s_ed[2] + s_ed[3]);
        if (isScat) {
            int tot  = (sc2[0] + sc2[1]) + (sc2[2] + sc2[3]);
            float tv = (sv[0] + sv[1]) + (sv[2] + sv[3]);
            count_out[b] = tot;
            vdot_out[b]  = (double)tv;
        }
    }
    int tot = (sc2[0] + sc2[1]) + (sc2[2] + sc2[3]);
    float recip = 1.0f / ((float)tot + EPSF);

    // ---- phase D: write recip at visited cells inside this chunk
    // (duplicates write the identical value; zeros already laid down)
    int lo = c * CHUNK, hi = lo + CHUNK;
    for (int idx = threadIdx.x; idx < P; idx += 256) {
        float px, py;
        comp_pt(gt, b, idx, ms, segN, px, py);
        int cell = pt_cell(px, py);
        if (cell >= lo && cell < hi)
            svf[(size_t)b * HW + cell] = recip;
    }
}

// ---------------------------------------------------------------------------
// Loss kernel (64 float partials per batch; accumulation stays double)
// ---------------------------------------------------------------------------
__global__ void loss_kernel(const float* __restrict__ esum_p,
                            const float* __restrict__ edot_p,
                            const double* __restrict__ vdot,
                            const int* __restrict__ count,
                            float* __restrict__ loss_out) {
    int b = threadIdx.x;  // 64 threads = 1 wave
    double es = 0.0, ed = 0.0;
    #pragma unroll 8
    for (int c = 0; c < 64; ++c) {
        es += (double)esum_p[b * 64 + c];
        ed += (double)edot_p[b * 64 + c];
    }
    double e = ed / (es + 1e-5);
    double v = vdot[b] / ((double)count[b] + 1e-5);
    double term = e - v;
    for (int off = 32; off; off >>= 1) term += __shfl_down(term, off);
    if (b == 0) loss_out[0] = (float)(term / (double)Bb);
}

extern "C" void kernel_launch(void* const* d_in, const int* in_sizes, int n_in,
                              void* d_out, int out_size, void* d_ws, size_t ws_size,
                              hipStream_t stream) {
    const float* gt   = (const float*)d_in[0];
    const float* exps = (const float*)d_in[1];
    const float* rew  = (const float*)d_in[2];
    float* out = (float*)d_out;

    float* loss_out = out;
    float* svf = out + 1;
    int P  = (out_size - 1 - Bb * HW) / (Bb * 2);
    int ms = (P - 1) / (Tt - 1);
    float* pts = out + 1 + (size_t)Bb * HW;

    int*    count  = (int*)d_ws;
    double* vdot   = (double*)((char*)d_ws + 256);
    float*  esum_p = (float*)((char*)d_ws + 768);
    float*  edot_p = (float*)((char*)d_ws + 17152);

    combined_kernel<<<RB, 256, 0, stream>>>(exps, rew, gt, pts, svf,
                                            esum_p, edot_p, count, vdot,
                                            ms, P);
    loss_kernel<<<1, 64, 0, stream>>>(esum_p, edot_p, vdot, count, loss_out);
}